// Round 2
// baseline (92.449 us; speedup 1.0000x reference)
//
#include <hip/hip_runtime.h>

// PatchDivider: reorder pts by serialization order, split into 64-point
// patches, subtract per-patch mean.
//
// R1: one wave handles PPW=4 patches (lane l = point l of each patch).
//  - 4 independent idx loads then 4 independent point gathers -> 4x MLP.
//  - 12-byte struct loads/stores -> global_load_dwordx3 (1 VMEM instr per
//    point instead of 3; align-4 multi-dword global access is fast on gfx950).
//
// B=32, N=131072, PATCH=64 -> 65536 patches.
// d_in[0]: pts    float32 [B*N*3]
// d_in[1]: orders int32   [B*N]
// d_out  : patches [B,L,64,3] then centers [B,L,3], float32, concatenated.

#define PD_B 32
#define PD_N 131072
#define PD_PATCH 64
#define PD_L (PD_N / PD_PATCH)          // 2048
#define PD_NPATCH (PD_B * PD_L)         // 65536
#define PPW 4                           // patches per wave

struct pt3 { float x, y, z; };          // size 12, align 4 -> dwordx3

__global__ __launch_bounds__(256) void PatchDivider_57621281243393_kernel(
    const float* __restrict__ pts,
    const int* __restrict__ orders,
    float* __restrict__ out)
{
    const int gtid = blockIdx.x * blockDim.x + threadIdx.x;
    const int wid  = gtid >> 6;                 // wave id: [0, 16384)
    const int lane = threadIdx.x & 63;
    const int patch0 = wid * PPW;

    // 4 coalesced idx loads (independent)
    int idx[PPW];
    #pragma unroll
    for (int k = 0; k < PPW; ++k)
        idx[k] = orders[(patch0 + k) * PD_PATCH + lane];

    // 4 independent random gathers, one dwordx3 each
    pt3 q[PPW];
    #pragma unroll
    for (int k = 0; k < PPW; ++k)
        q[k] = *(const pt3*)(pts + (size_t)idx[k] * 3);

    const float inv = 1.0f / (float)PD_PATCH;

    #pragma unroll
    for (int k = 0; k < PPW; ++k) {
        // wave-wide 64-lane butterfly sum
        float sx = q[k].x, sy = q[k].y, sz = q[k].z;
        #pragma unroll
        for (int off = 32; off >= 1; off >>= 1) {
            sx += __shfl_xor(sx, off, 64);
            sy += __shfl_xor(sy, off, 64);
            sz += __shfl_xor(sz, off, 64);
        }
        const float cx = sx * inv;
        const float cy = sy * inv;
        const float cz = sz * inv;

        // centered point -> contiguous 768B span per patch (dwordx3 store)
        const int point = (patch0 + k) * PD_PATCH + lane;
        pt3 r = { q[k].x - cx, q[k].y - cy, q[k].z - cz };
        *(pt3*)(out + (size_t)point * 3) = r;

        if (lane == 0) {
            pt3 c = { cx, cy, cz };
            *(pt3*)(out + (size_t)PD_NPATCH * PD_PATCH * 3
                        + (size_t)(patch0 + k) * 3) = c;
        }
    }
}

extern "C" void kernel_launch(void* const* d_in, const int* in_sizes, int n_in,
                              void* d_out, int out_size, void* d_ws, size_t ws_size,
                              hipStream_t stream) {
    const float* pts  = (const float*)d_in[0];
    const int* orders = (const int*)d_in[1];
    float* out        = (float*)d_out;

    const int waves = PD_NPATCH / PPW;          // 16384
    const int block = 256;                      // 4 waves/block
    const int grid  = waves * 64 / block;       // 4096

    PatchDivider_57621281243393_kernel<<<grid, block, 0, stream>>>(pts, orders, out);
}